// Round 16
// baseline (2061.188 us; speedup 1.0000x reference)
//
#include <hip/hip_runtime.h>
#include <hip/hip_bf16.h>
#include <stdint.h>

typedef __bf16 bf16;
typedef __bf16 bf16x8 __attribute__((ext_vector_type(8)));
typedef float f32x4 __attribute__((ext_vector_type(4)));

typedef uint32_t __attribute__((address_space(1))) * gptr_as1;
typedef uint32_t __attribute__((address_space(3))) * lptr_as3;

__device__ __forceinline__ void async16(const void* g, void* l) {
    __builtin_amdgcn_global_load_lds((gptr_as1)(uintptr_t)g,
                                     (lptr_as3)(uintptr_t)l,
                                     16, 0, 0);
}

__device__ __forceinline__ void bar() {
    asm volatile("" ::: "memory");
    __builtin_amdgcn_s_barrier();
    asm volatile("" ::: "memory");
}

// ---------------------------------------------------------------- cvt f32->bf16
__global__ void cvt_f32_bf16_kernel(const float* __restrict__ src,
                                    bf16* __restrict__ dst, int n8) {
    int i = blockIdx.x * blockDim.x + threadIdx.x;
    if (i >= n8) return;
    const float4* s = reinterpret_cast<const float4*>(src);
    float4 a = s[2 * (size_t)i], b = s[2 * (size_t)i + 1];
    bf16x8 v;
    v[0] = (bf16)a.x; v[1] = (bf16)a.y; v[2] = (bf16)a.z; v[3] = (bf16)a.w;
    v[4] = (bf16)b.x; v[5] = (bf16)b.y; v[6] = (bf16)b.z; v[7] = (bf16)b.w;
    *reinterpret_cast<bf16x8*>(dst + (size_t)i * 8) = v;
}

// cvt + 16-row interleave: src row r (of DHID) -> dst row (r/16)*32 + sel*16 + r%16.
__global__ void cvt_ilv_kernel(const float* __restrict__ src,
                               bf16* __restrict__ dst, int n8, int sel) {
    int i = blockIdx.x * blockDim.x + threadIdx.x;
    if (i >= n8) return;
    const int row = i >> 8;          // / 256  (DIN=2048 -> 256 chunks/row)
    const int c = i & 255;
    const int drow = ((row >> 4) << 5) + (sel << 4) + (row & 15);
    const float4* s = reinterpret_cast<const float4*>(src);
    float4 a = s[2 * (size_t)i], b = s[2 * (size_t)i + 1];
    bf16x8 v;
    v[0] = (bf16)a.x; v[1] = (bf16)a.y; v[2] = (bf16)a.z; v[3] = (bf16)a.w;
    v[4] = (bf16)b.x; v[5] = (bf16)b.y; v[6] = (bf16)b.z; v[7] = (bf16)b.w;
    *reinterpret_cast<bf16x8*>(dst + ((size_t)drow * 256 + c) * 8) = v;
}

// ---------------------------------------------------------------- 256^2 GEMM, BK=32, 4-slot circular LDS, ONE barrier/tile
// C = A[M,K]*B[N,K]^T. 512 thr / 8 waves (2Mx4N), wave tile 128x64.
// LDS: 4 slots x (A[256][32] 16K + B[256][32] 16K) = 128 KB.
// Tile kt body: [stage(kt+3)->slot (kt+3)&3 (4 gloads); 12 ds_reads (bv then av,
//   base+literal, zero VALU); 32 MFMA (compiler-counted lgkm -> waves SLIP);
//   counted vmcnt; ONE barrier].
// WAR (structural, no timing assumptions): slot (kt+3)&3 == (kt-1)&3 was last
//   read in tile kt-1; every wave's reads are lgkm-consumed by its own MFMAs
//   before it passes tile kt-1's barrier, and that barrier precedes this stage.
// RAW: end-of-tile-kt vmcnt(8) keeps {kt+2,kt+3}'s 8, lands kt+1's 4; barrier
//   publishes. Tail: vmcnt(4) @NT-3, vmcnt(0) @NT-2. Prologue: tiles 0,1,2 ->
//   slots 0,1,2; vmcnt(8) lands tile0.
// Read swizzle (R14-measured, SQ_LDS_BANK_CONFLICT=0): 64B row pitch,
//   byte = row*64 + (chi ^ (((row>>1)&3)<<4)); row>>1 term is per-lane const
//   (other row terms ≡ 0 mod 4) -> reads are loop-invariant base + literal.
// Staging source involution (R14-verbatim): sg = ((l&3) ^ ((l>>3)&3))<<4,
//   dest linear (rule 21).
// EPI=0: bf16(gelu(acc*s1)) | EPI=1: f32(acc*s1) | EPI=2: swiglu, 16-col interleave.
template <int EPI, int K>
__global__ __launch_bounds__(512, 1)
void gemm4s(const bf16* __restrict__ A, const bf16* __restrict__ B,
            void* __restrict__ Cout, const float* __restrict__ s1p,
            const float* __restrict__ s2p, int N, int ldh) {
    __shared__ __align__(16) char sm[131072];

    const int tid = threadIdx.x;
    const int w = tid >> 6, l = tid & 63;
    const int wr = w >> 2, wc = w & 3;

    const int gx = gridDim.x;
    const int nwg = gx * (int)gridDim.y;
    const int orig = blockIdx.y * gx + blockIdx.x;
    const int wg = (orig & 7) * (nwg >> 3) + (orig >> 3);
    const int bm = wg / gx, bn = wg % gx;

    constexpr int NT = K / 32;   // NT divisible by 4 for all our K (2048, 8192)

    f32x4 acc[8][4] = {};

    const int arow = bm * 256, brow = bn * 256;

    // ---- staging pointers (advance +64 B per staged tile)
    const int sr = l >> 2;                               // row-in-16-row-slab
    const int sg = ((l & 3) ^ ((l >> 3) & 3)) << 4;      // source involution
    const char* qa0 = (const char*)(A + (size_t)(arow +   0 + w * 16 + sr) * K) + sg;
    const char* qa1 = (const char*)(A + (size_t)(arow + 128 + w * 16 + sr) * K) + sg;
    const char* qb0 = (const char*)(B + (size_t)(brow +   0 + w * 16 + sr) * K) + sg;
    const char* qb1 = (const char*)(B + (size_t)(brow + 128 + w * 16 + sr) * K) + sg;
    const int ldw = w * 1024;
    auto STAGE_TILE = [&](char* slot) {   // one 32KB tile -> slot
        async16(qa0, slot +     0 + ldw);
        async16(qa1, slot +  8192 + ldw);
        async16(qb0, slot + 16384 + ldw);
        async16(qb1, slot + 24576 + ldw);
        qa0 += 64; qa1 += 64; qb0 += 64; qb1 += 64;
    };

    // ---- per-lane LDS read bases (loop-invariant; reads = base + literal)
    const int rlane = l & 15;
    const int chi = (l >> 4) << 4;
    const int swz = ((rlane >> 1) & 3) << 4;
    const int offA = (wr * 128 + rlane) * 64 + (chi ^ swz);
    const int offB = (wc * 64 + rlane) * 64 + (chi ^ swz);
    const char* const pA0 = sm +      0 + offA;
    const char* const pA1 = sm +  32768 + offA;
    const char* const pA2 = sm +  65536 + offA;
    const char* const pA3 = sm +  98304 + offA;
    const char* const pB0 = sm +  16384 + offB;
    const char* const pB1 = sm +  49152 + offB;
    const char* const pB2 = sm +  81920 + offB;
    const char* const pB3 = sm + 114688 + offB;

    // ---- prologue: tiles 0,1,2 -> slots 0,1,2
    STAGE_TILE(sm);
    STAGE_TILE(sm + 32768);
    STAGE_TILE(sm + 65536);
    asm volatile("s_waitcnt vmcnt(8)" ::: "memory");   // tile0's 4 landed
    bar();

    auto body = [&](int kt, const char* pa, const char* pb, char* nslot) {
        if (kt + 3 < NT) STAGE_TILE(nslot);
        bf16x8 bv[4], av[8];
#pragma unroll
        for (int j = 0; j < 4; ++j)
            bv[j] = *reinterpret_cast<const bf16x8*>(pb + j * 1024);
#pragma unroll
        for (int i = 0; i < 8; ++i)
            av[i] = *reinterpret_cast<const bf16x8*>(pa + i * 1024);
        __builtin_amdgcn_s_setprio(1);
#pragma unroll
        for (int i = 0; i < 8; ++i)
#pragma unroll
            for (int j = 0; j < 4; ++j)
                acc[i][j] = __builtin_amdgcn_mfma_f32_16x16x32_bf16(av[i], bv[j], acc[i][j], 0, 0, 0);
        __builtin_amdgcn_s_setprio(0);
        if (kt + 3 < NT)      { asm volatile("s_waitcnt vmcnt(8)" ::: "memory"); }
        else if (kt == NT - 3) { asm volatile("s_waitcnt vmcnt(4)" ::: "memory"); }
        else if (kt == NT - 2) { asm volatile("s_waitcnt vmcnt(0)" ::: "memory"); }
        bar();
    };

#pragma unroll 1
    for (int kt = 0; kt < NT; kt += 4) {
        body(kt + 0, pA0, pB0, sm + 98304);   // stages kt+3 -> slot 3
        body(kt + 1, pA1, pB1, sm);           // stages kt+4 -> slot 0
        body(kt + 2, pA2, pB2, sm + 32768);   // stages kt+5 -> slot 1
        body(kt + 3, pA3, pB3, sm + 65536);   // stages kt+6 -> slot 2
    }

    const float s1 = s1p[0];
    const int r0 = bm * 256 + wr * 128 + ((l >> 4) << 2);
    if constexpr (EPI == 2) {
        const float s2 = s2p[0];
        const int hcb = (bn * 8 + wc * 2) * 16 + rlane;
#pragma unroll
        for (int i = 0; i < 8; ++i)
#pragma unroll
            for (int jp = 0; jp < 2; ++jp)
#pragma unroll
                for (int q = 0; q < 4; ++q) {
                    float g = acc[i][2 * jp][q] * s1;
                    float v = acc[i][2 * jp + 1][q] * s2;
                    float sig = 1.0f / (1.0f + __expf(-g));
                    ((bf16*)Cout)[(size_t)(r0 + i * 16 + q) * ldh + hcb + jp * 16] =
                        (bf16)(g * sig * v);
                }
    } else {
        const int c0 = bn * 256 + wc * 64 + rlane;
#pragma unroll
        for (int i = 0; i < 8; ++i)
#pragma unroll
            for (int j = 0; j < 4; ++j)
#pragma unroll
                for (int q = 0; q < 4; ++q) {
                    float v = acc[i][j][q] * s1;
                    size_t idx = (size_t)(r0 + i * 16 + q) * N + (c0 + j * 16);
                    if constexpr (EPI == 0) {
                        float g = 0.5f * v * (1.0f + erff(v * 0.70710678118654752f));
                        ((bf16*)Cout)[idx] = (bf16)g;
                    } else {
                        ((float*)Cout)[idx] = v;
                    }
                }
    }
}

// ---------------------------------------------------------------- launch
extern "C" void kernel_launch(void* const* d_in, const int* in_sizes, int n_in,
                              void* d_out, int out_size, void* d_ws, size_t ws_size,
                              hipStream_t stream) {
    constexpr int NTOK = 8192, DIN = 2048, DHID = 8192;

    const float* x  = (const float*)d_in[0];
    const float* W1 = (const float*)d_in[1];
    const float* W2 = (const float*)d_in[2];
    const float* Wh = (const float*)d_in[3];
    const float* W3 = (const float*)d_in[4];
    const float* s1 = (const float*)d_in[5];
    const float* s2 = (const float*)d_in[6];
    const float* sh = (const float*)d_in[7];
    const float* s3 = (const float*)d_in[8];
    float* out = (float*)d_out;

    char* ws = (char*)d_ws;
    size_t off = 0;
    bf16* xb   = (bf16*)(ws + off); off += (size_t)NTOK * DIN * 2;
    bf16* w12b = (bf16*)(ws + off); off += (size_t)2 * DHID * DIN * 2;
    bf16* w3b  = (bf16*)(ws + off); off += (size_t)DIN * DHID * 2;
    bf16* whb  = (bf16*)(ws + off); off += (size_t)DHID * DHID * 2;
    bf16* h1   = (bf16*)(ws + off); off += (size_t)NTOK * DHID * 2;
    bf16* h2   = (bf16*)(ws + off); off += (size_t)NTOK * DHID * 2;
    if (ws_size < off) return;

    auto cvt = [&](const float* s, bf16* d, size_t n) {
        int n8 = (int)(n / 8);
        cvt_f32_bf16_kernel<<<(n8 + 255) / 256, 256, 0, stream>>>(s, d, n8);
    };
    cvt(x,  xb,  (size_t)NTOK * DIN);
    cvt(Wh, whb, (size_t)DHID * DHID);
    cvt(W3, w3b, (size_t)DIN * DHID);
    {
        int n8 = (int)((size_t)DHID * DIN / 8);
        cvt_ilv_kernel<<<(n8 + 255) / 256, 256, 0, stream>>>(W1, w12b, n8, 0);
        cvt_ilv_kernel<<<(n8 + 255) / 256, 256, 0, stream>>>(W2, w12b, n8, 1);
    }

    // GEMM1+2 fused: C[8192, 16384] over interleaved W12, SwiGLU epilogue -> h1
    gemm4s<2, DIN><<<dim3(2 * DHID / 256, NTOK / 256), 512, 0, stream>>>(
        xb, w12b, h1, s1, s2, 2 * DHID, DHID);
    // hidden GEMM + gelu -> h2
    gemm4s<0, DHID><<<dim3(DHID / 256, NTOK / 256), 512, 0, stream>>>(
        h1, whb, h2, sh, sh, DHID, DHID);
    // output GEMM -> out (f32)
    gemm4s<1, DHID><<<dim3(DIN / 256, NTOK / 256), 512, 0, stream>>>(
        h2, w3b, out, s3, s3, DIN, DIN);
}

// Round 18
// 1968.402 us; speedup vs baseline: 1.0471x; 1.0471x over previous
//
#include <hip/hip_runtime.h>
#include <hip/hip_bf16.h>
#include <stdint.h>

typedef __bf16 bf16;
typedef __bf16 bf16x8 __attribute__((ext_vector_type(8)));
typedef float f32x4 __attribute__((ext_vector_type(4)));

typedef uint32_t __attribute__((address_space(1))) * gptr_as1;
typedef uint32_t __attribute__((address_space(3))) * lptr_as3;

__device__ __forceinline__ void async16(const void* g, void* l) {
    __builtin_amdgcn_global_load_lds((gptr_as1)(uintptr_t)g,
                                     (lptr_as3)(uintptr_t)l,
                                     16, 0, 0);
}

__device__ __forceinline__ void bar() {
    asm volatile("" ::: "memory");
    __builtin_amdgcn_s_barrier();
    asm volatile("" ::: "memory");
}

// ---------------------------------------------------------------- cvt f32->bf16
__global__ void cvt_f32_bf16_kernel(const float* __restrict__ src,
                                    bf16* __restrict__ dst, int n8) {
    int i = blockIdx.x * blockDim.x + threadIdx.x;
    if (i >= n8) return;
    const float4* s = reinterpret_cast<const float4*>(src);
    float4 a = s[2 * (size_t)i], b = s[2 * (size_t)i + 1];
    bf16x8 v;
    v[0] = (bf16)a.x; v[1] = (bf16)a.y; v[2] = (bf16)a.z; v[3] = (bf16)a.w;
    v[4] = (bf16)b.x; v[5] = (bf16)b.y; v[6] = (bf16)b.z; v[7] = (bf16)b.w;
    *reinterpret_cast<bf16x8*>(dst + (size_t)i * 8) = v;
}

// cvt + 16-row interleave: src row r (of DHID) -> dst row (r/16)*32 + sel*16 + r%16.
__global__ void cvt_ilv_kernel(const float* __restrict__ src,
                               bf16* __restrict__ dst, int n8, int sel) {
    int i = blockIdx.x * blockDim.x + threadIdx.x;
    if (i >= n8) return;
    const int row = i >> 8;          // / 256  (DIN=2048 -> 256 chunks/row)
    const int c = i & 255;
    const int drow = ((row >> 4) << 5) + (sel << 4) + (row & 15);
    const float4* s = reinterpret_cast<const float4*>(src);
    float4 a = s[2 * (size_t)i], b = s[2 * (size_t)i + 1];
    bf16x8 v;
    v[0] = (bf16)a.x; v[1] = (bf16)a.y; v[2] = (bf16)a.z; v[3] = (bf16)a.w;
    v[4] = (bf16)b.x; v[5] = (bf16)b.y; v[6] = (bf16)b.z; v[7] = (bf16)b.w;
    *reinterpret_cast<bf16x8*>(dst + ((size_t)drow * 256 + c) * 8) = v;
}

// ---------------------------------------------------------------- 256^2 GEMM, BK=32, 4-slot circular, PAIR staging (grouped order)
// C = A[M,K]*B[N,K]^T. 512 thr / 8 waves (2Mx4N), wave tile 128x64.
// LDS: 4 slots x (A[256][32] 16K + B[256][32] 16K) = 128 KB. One barrier/tile,
// wave-slip (MFMA gated only by own compiler-counted lgkm).
// R17 FAILURE FIX: STAGE_PAIR previously interleaved even/odd tile loads, so
// the FIFO's oldest-4 were NOT one tile's 4 loads and every counted vmcnt
// landed the wrong set (race, absmax 0.087). NOW grouped: even tile's 4 loads
// first, then odd tile's 4 — ledger is exact. L2 line pairing survives (the
// two 64B halves of each 128B line are ~3 instrs apart, vs a full tile in R16
// which doubled FETCH).
// Ledger (8 loads/pair, grouped): prologue vmcnt(4) lands tile0 exactly;
// body_even(kt) stages pair{kt+2,kt+3}, end vmcnt(8) keeps that pair, lands
// all of kt+1; body_odd(kt+1) end vmcnt(4) keeps tile kt+3's 4, lands kt+2;
// tail: vmcnt(0) at kt=NT-2 (no stage), none at NT-1. NT%4==0.
// WAR (structural): slot (kt+3)&3 = (kt-1)&3 last read in tile kt-1, whose
// reads were lgkm-consumed (by that wave's MFMAs) before tile kt-1's barrier,
// which precedes this stage.
// Reads: measured conflict-free (64B pitch, byte = row*64 +
// (chi ^ (((row>>1)&3)<<4)), per-lane const swizzle -> base + literal).
// EPI=0: bf16(gelu(acc*s1)) | EPI=1: f32(acc*s1) | EPI=2: swiglu, 16-col interleave.
template <int EPI, int K>
__global__ __launch_bounds__(512, 1)
void gemm4sp(const bf16* __restrict__ A, const bf16* __restrict__ B,
             void* __restrict__ Cout, const float* __restrict__ s1p,
             const float* __restrict__ s2p, int N, int ldh) {
    __shared__ __align__(16) char sm[131072];

    const int tid = threadIdx.x;
    const int w = tid >> 6, l = tid & 63;
    const int wr = w >> 2, wc = w & 3;

    const int gx = gridDim.x;
    const int nwg = gx * (int)gridDim.y;
    const int orig = blockIdx.y * gx + blockIdx.x;
    const int wg = (orig & 7) * (nwg >> 3) + (orig >> 3);
    const int bm = wg / gx, bn = wg % gx;

    constexpr int NT = K / 32;

    f32x4 acc[8][4] = {};

    const int arow = bm * 256, brow = bn * 256;

    // ---- staging pointers (advance +128 B per staged pair)
    const int sr = l >> 2;
    const int sg = ((l & 3) ^ ((l >> 3) & 3)) << 4;
    const char* qa0 = (const char*)(A + (size_t)(arow +   0 + w * 16 + sr) * K) + sg;
    const char* qa1 = (const char*)(A + (size_t)(arow + 128 + w * 16 + sr) * K) + sg;
    const char* qb0 = (const char*)(B + (size_t)(brow +   0 + w * 16 + sr) * K) + sg;
    const char* qb1 = (const char*)(B + (size_t)(brow + 128 + w * 16 + sr) * K) + sg;
    const int ldw = w * 1024;
    // GROUPED issue order: even tile's 4 loads, THEN odd tile's 4 loads.
    auto STAGE_PAIR = [&](char* se, char* so) {
        async16(qa0,      se +     0 + ldw);
        async16(qa1,      se +  8192 + ldw);
        async16(qb0,      se + 16384 + ldw);
        async16(qb1,      se + 24576 + ldw);
        async16(qa0 + 64, so +     0 + ldw);
        async16(qa1 + 64, so +  8192 + ldw);
        async16(qb0 + 64, so + 16384 + ldw);
        async16(qb1 + 64, so + 24576 + ldw);
        qa0 += 128; qa1 += 128; qb0 += 128; qb1 += 128;
    };

    // ---- per-lane LDS read bases (loop-invariant; reads = base + literal)
    const int rlane = l & 15;
    const int chi = (l >> 4) << 4;
    const int swz = ((rlane >> 1) & 3) << 4;
    const int offA = (wr * 128 + rlane) * 64 + (chi ^ swz);
    const int offB = (wc * 64 + rlane) * 64 + (chi ^ swz);
    const char* const pA0 = sm +      0 + offA;
    const char* const pA1 = sm +  32768 + offA;
    const char* const pA2 = sm +  65536 + offA;
    const char* const pA3 = sm +  98304 + offA;
    const char* const pB0 = sm +  16384 + offB;
    const char* const pB1 = sm +  49152 + offB;
    const char* const pB2 = sm +  81920 + offB;
    const char* const pB3 = sm + 114688 + offB;

    // ---- prologue: pair {0,1} -> slots 0,1; vmcnt(4) lands tile0's 4 (oldest)
    STAGE_PAIR(sm, sm + 32768);
    asm volatile("s_waitcnt vmcnt(4)" ::: "memory");
    bar();

    auto compute = [&](const char* pa, const char* pb) {
        bf16x8 bv[4], av[8];
#pragma unroll
        for (int j = 0; j < 4; ++j)
            bv[j] = *reinterpret_cast<const bf16x8*>(pb + j * 1024);
#pragma unroll
        for (int i = 0; i < 8; ++i)
            av[i] = *reinterpret_cast<const bf16x8*>(pa + i * 1024);
        __builtin_amdgcn_s_setprio(1);
#pragma unroll
        for (int i = 0; i < 8; ++i)
#pragma unroll
            for (int j = 0; j < 4; ++j)
                acc[i][j] = __builtin_amdgcn_mfma_f32_16x16x32_bf16(av[i], bv[j], acc[i][j], 0, 0, 0);
        __builtin_amdgcn_s_setprio(0);
    };

    auto body_even = [&](int kt, const char* pa, const char* pb, char* se, char* so) {
        if (kt + 2 < NT) STAGE_PAIR(se, so);
        compute(pa, pb);
        if (kt + 2 < NT) { asm volatile("s_waitcnt vmcnt(8)" ::: "memory"); }
        else             { asm volatile("s_waitcnt vmcnt(0)" ::: "memory"); }
        bar();
    };
    auto body_odd = [&](int kt, const char* pa, const char* pb) {
        compute(pa, pb);
        if (kt + 1 < NT) { asm volatile("s_waitcnt vmcnt(4)" ::: "memory"); }
        bar();
    };

#pragma unroll 1
    for (int kt = 0; kt < NT; kt += 4) {
        body_even(kt + 0, pA0, pB0, sm + 65536, sm + 98304);  // stage {kt+2,kt+3} -> slots 2,3
        body_odd (kt + 1, pA1, pB1);
        body_even(kt + 2, pA2, pB2, sm, sm + 32768);          // stage {kt+4,kt+5} -> slots 0,1
        body_odd (kt + 3, pA3, pB3);
    }

    const float s1 = s1p[0];
    const int r0 = bm * 256 + wr * 128 + ((l >> 4) << 2);
    if constexpr (EPI == 2) {
        const float s2 = s2p[0];
        const int hcb = (bn * 8 + wc * 2) * 16 + rlane;
#pragma unroll
        for (int i = 0; i < 8; ++i)
#pragma unroll
            for (int jp = 0; jp < 2; ++jp)
#pragma unroll
                for (int q = 0; q < 4; ++q) {
                    float g = acc[i][2 * jp][q] * s1;
                    float v = acc[i][2 * jp + 1][q] * s2;
                    float sig = 1.0f / (1.0f + __expf(-g));
                    ((bf16*)Cout)[(size_t)(r0 + i * 16 + q) * ldh + hcb + jp * 16] =
                        (bf16)(g * sig * v);
                }
    } else {
        const int c0 = bn * 256 + wc * 64 + rlane;
#pragma unroll
        for (int i = 0; i < 8; ++i)
#pragma unroll
            for (int j = 0; j < 4; ++j)
#pragma unroll
                for (int q = 0; q < 4; ++q) {
                    float v = acc[i][j][q] * s1;
                    size_t idx = (size_t)(r0 + i * 16 + q) * N + (c0 + j * 16);
                    if constexpr (EPI == 0) {
                        float g = 0.5f * v * (1.0f + erff(v * 0.70710678118654752f));
                        ((bf16*)Cout)[idx] = (bf16)g;
                    } else {
                        ((float*)Cout)[idx] = v;
                    }
                }
    }
}

// ---------------------------------------------------------------- R15 proven wave-slip gemm8p (GEMM12 / GEMM3)
template <int EPI, int K>
__global__ __launch_bounds__(512, 1)
void gemm8p(const bf16* __restrict__ A, const bf16* __restrict__ B,
            void* __restrict__ Cout, const float* __restrict__ s1p,
            const float* __restrict__ s2p, int N, int ldh) {
    __shared__ __align__(16) char sm[131072];

    const int tid = threadIdx.x;
    const int w = tid >> 6, l = tid & 63;
    const int wr = w >> 2, wc = w & 3;

    const int gx = gridDim.x;
    const int nwg = gx * (int)gridDim.y;
    const int orig = blockIdx.y * gx + blockIdx.x;
    const int wg = (orig & 7) * (nwg >> 3) + (orig >> 3);
    const int bm = wg / gx, bn = wg % gx;

    constexpr int NT = K / 64;

    f32x4 acc[8][4] = {};

    char* const bufA0 = sm;
    char* const bufB0 = sm + 32768;
    char* const bufA1 = sm + 65536;
    char* const bufB1 = sm + 98304;
    const int arow = bm * 256, brow = bn * 256;

    const int srow_in = l >> 3;
    const int scolb = ((l & 7) ^ srow_in) << 4;
    auto STAGE = [&](char* ldsT, const bf16* g, int grow0, int kt, int r0) {
        const int rr = r0 + w * 8 + srow_in;
        const char* gp = (const char*)(g + (size_t)(grow0 + rr) * K + kt * 64) + scolb;
        async16(gp, ldsT + r0 * 128 + w * 1024);
    };

    const int rlane = l & 15;
    const int chi = (l >> 4) << 4;
    const int sw = (rlane & 7) << 4;
    const int ksd = (rlane & 4) ? -64 : 64;
    const int offA = (wr * 128 + rlane) * 128 + (chi ^ sw);
    const int offB = (wc * 64 + rlane) * 128 + (chi ^ sw);
    const char* const pA0  = bufA0 + offA;  const char* const pA0k = pA0 + ksd;
    const char* const pB0  = bufB0 + offB;  const char* const pB0k = pB0 + ksd;
    const char* const pA1  = bufA1 + offA;  const char* const pA1k = pA1 + ksd;
    const char* const pB1  = bufB1 + offB;  const char* const pB1k = pB1 + ksd;

    STAGE(bufA0, A, arow, 0, 0);   STAGE(bufA0, A, arow, 0, 128);
    STAGE(bufB0, B, brow, 0, 0);   STAGE(bufB0, B, brow, 0, 64);
    STAGE(bufB0, B, brow, 0, 128); STAGE(bufB0, B, brow, 0, 192);
    STAGE(bufA0, A, arow, 0, 64);  STAGE(bufA0, A, arow, 0, 192);
    STAGE(bufA1, A, arow, 1, 0);   STAGE(bufA1, A, arow, 1, 128);
    STAGE(bufB1, B, brow, 1, 0);   STAGE(bufB1, B, brow, 1, 64);
    STAGE(bufB1, B, brow, 1, 128); STAGE(bufB1, B, brow, 1, 192);
    asm volatile("s_waitcnt vmcnt(6)" ::: "memory");
    bar();

    auto body = [&](int kt, char* cA, char* cB, char* nA,
                    const char* pa, const char* pak,
                    const char* pb, const char* pbk) {
        bf16x8 ae[4], ao[4], bv[4];
        if (kt + 1 < NT) { STAGE(nA, A, arow, kt + 1, 64); STAGE(nA, A, arow, kt + 1, 192); }
#pragma unroll
        for (int i = 0; i < 4; ++i)
            ae[i] = *reinterpret_cast<const bf16x8*>(pa + i * 2048);
#pragma unroll
        for (int j = 0; j < 4; ++j)
            bv[j] = *reinterpret_cast<const bf16x8*>(pb + j * 2048);
        __builtin_amdgcn_s_setprio(1);
#pragma unroll
        for (int i = 0; i < 4; ++i)
#pragma unroll
            for (int j = 0; j < 4; ++j)
                acc[i][j] = __builtin_amdgcn_mfma_f32_16x16x32_bf16(ae[i], bv[j], acc[i][j], 0, 0, 0);
        __builtin_amdgcn_s_setprio(0);
        bar();
#pragma unroll
        for (int i = 0; i < 4; ++i)
            ao[i] = *reinterpret_cast<const bf16x8*>(pa + 8192 + i * 2048);
        __builtin_amdgcn_s_setprio(1);
#pragma unroll
        for (int i = 0; i < 4; ++i)
#pragma unroll
            for (int j = 0; j < 4; ++j)
                acc[4 + i][j] = __builtin_amdgcn_mfma_f32_16x16x32_bf16(ao[i], bv[j], acc[4 + i][j], 0, 0, 0);
        __builtin_amdgcn_s_setprio(0);
        bar();
#pragma unroll
        for (int i = 0; i < 4; ++i)
            ae[i] = *reinterpret_cast<const bf16x8*>(pak + i * 2048);
#pragma unroll
        for (int j = 0; j < 4; ++j)
            bv[j] = *reinterpret_cast<const bf16x8*>(pbk + j * 2048);
        __builtin_amdgcn_s_setprio(1);
#pragma unroll
        for (int i = 0; i < 4; ++i)
#pragma unroll
            for (int j = 0; j < 4; ++j)
                acc[i][j] = __builtin_amdgcn_mfma_f32_16x16x32_bf16(ae[i], bv[j], acc[i][j], 0, 0, 0);
        __builtin_amdgcn_s_setprio(0);
        bar();
        if (kt + 2 < NT) {
            STAGE(cB, B, brow, kt + 2, 0);   STAGE(cB, B, brow, kt + 2, 64);
            STAGE(cB, B, brow, kt + 2, 128); STAGE(cB, B, brow, kt + 2, 192);
            STAGE(cA, A, arow, kt + 2, 0);   STAGE(cA, A, arow, kt + 2, 128);
        }
#pragma unroll
        for (int i = 0; i < 4; ++i)
            ao[i] = *reinterpret_cast<const bf16x8*>(pak + 8192 + i * 2048);
        __builtin_amdgcn_s_setprio(1);
#pragma unroll
        for (int i = 0; i < 4; ++i)
#pragma unroll
            for (int j = 0; j < 4; ++j)
                acc[4 + i][j] = __builtin_amdgcn_mfma_f32_16x16x32_bf16(ao[i], bv[j], acc[4 + i][j], 0, 0, 0);
        __builtin_amdgcn_s_setprio(0);
        if (kt == NT - 2) { asm volatile("s_waitcnt vmcnt(0)" ::: "memory"); }
        else              { asm volatile("s_waitcnt vmcnt(6)" ::: "memory"); }
        bar();
    };

#pragma unroll 1
    for (int kt = 0; kt < NT; kt += 2) {
        body(kt,     bufA0, bufB0, bufA1, pA0, pA0k, pB0, pB0k);
        body(kt + 1, bufA1, bufB1, bufA0, pA1, pA1k, pB1, pB1k);
    }

    const float s1 = s1p[0];
    const int r0 = bm * 256 + wr * 128 + ((l >> 4) << 2);
    if constexpr (EPI == 2) {
        const float s2 = s2p[0];
        const int hcb = (bn * 8 + wc * 2) * 16 + rlane;
#pragma unroll
        for (int i = 0; i < 8; ++i)
#pragma unroll
            for (int jp = 0; jp < 2; ++jp)
#pragma unroll
                for (int q = 0; q < 4; ++q) {
                    float g = acc[i][2 * jp][q] * s1;
                    float v = acc[i][2 * jp + 1][q] * s2;
                    float sig = 1.0f / (1.0f + __expf(-g));
                    ((bf16*)Cout)[(size_t)(r0 + i * 16 + q) * ldh + hcb + jp * 16] =
                        (bf16)(g * sig * v);
                }
    } else {
        const int c0 = bn * 256 + wc * 64 + rlane;
#pragma unroll
        for (int i = 0; i < 8; ++i)
#pragma unroll
            for (int j = 0; j < 4; ++j)
#pragma unroll
                for (int q = 0; q < 4; ++q) {
                    float v = acc[i][j][q] * s1;
                    size_t idx = (size_t)(r0 + i * 16 + q) * N + (c0 + j * 16);
                    if constexpr (EPI == 0) {
                        float g = 0.5f * v * (1.0f + erff(v * 0.70710678118654752f));
                        ((bf16*)Cout)[idx] = (bf16)g;
                    } else {
                        ((float*)Cout)[idx] = v;
                    }
                }
    }
}

// ---------------------------------------------------------------- launch
extern "C" void kernel_launch(void* const* d_in, const int* in_sizes, int n_in,
                              void* d_out, int out_size, void* d_ws, size_t ws_size,
                              hipStream_t stream) {
    constexpr int NTOK = 8192, DIN = 2048, DHID = 8192;

    const float* x  = (const float*)d_in[0];
    const float* W1 = (const float*)d_in[1];
    const float* W2 = (const float*)d_in[2];
    const float* Wh = (const float*)d_in[3];
    const float* W3 = (const float*)d_in[4];
    const float* s1 = (const float*)d_in[5];
    const float* s2 = (const float*)d_in[6];
    const float* sh = (const float*)d_in[7];
    const float* s3 = (const float*)d_in[8];
    float* out = (float*)d_out;

    char* ws = (char*)d_ws;
    size_t off = 0;
    bf16* xb   = (bf16*)(ws + off); off += (size_t)NTOK * DIN * 2;
    bf16* w12b = (bf16*)(ws + off); off += (size_t)2 * DHID * DIN * 2;
    bf16* w3b  = (bf16*)(ws + off); off += (size_t)DIN * DHID * 2;
    bf16* whb  = (bf16*)(ws + off); off += (size_t)DHID * DHID * 2;
    bf16* h1   = (bf16*)(ws + off); off += (size_t)NTOK * DHID * 2;
    bf16* h2   = (bf16*)(ws + off); off += (size_t)NTOK * DHID * 2;
    if (ws_size < off) return;

    auto cvt = [&](const float* s, bf16* d, size_t n) {
        int n8 = (int)(n / 8);
        cvt_f32_bf16_kernel<<<(n8 + 255) / 256, 256, 0, stream>>>(s, d, n8);
    };
    cvt(x,  xb,  (size_t)NTOK * DIN);
    cvt(Wh, whb, (size_t)DHID * DHID);
    cvt(W3, w3b, (size_t)DIN * DHID);
    {
        int n8 = (int)((size_t)DHID * DIN / 8);
        cvt_ilv_kernel<<<(n8 + 255) / 256, 256, 0, stream>>>(W1, w12b, n8, 0);
        cvt_ilv_kernel<<<(n8 + 255) / 256, 256, 0, stream>>>(W2, w12b, n8, 1);
    }

    // GEMM1+2 fused (R15 gemm8p): C[8192, 16384] -> swiglu -> h1
    gemm8p<2, DIN><<<dim3(2 * DHID / 256, NTOK / 256), 512, 0, stream>>>(
        xb, w12b, h1, s1, s2, 2 * DHID, DHID);
    // hidden GEMM + gelu -> h2  (pair-staged 4-slot kernel, grouped-order fix)
    gemm4sp<0, DHID><<<dim3(DHID / 256, NTOK / 256), 512, 0, stream>>>(
        h1, whb, h2, sh, sh, DHID, DHID);
    // output GEMM -> out (f32) (R15 gemm8p)
    gemm8p<1, DHID><<<dim3(DIN / 256, NTOK / 256), 512, 0, stream>>>(
        h2, w3b, out, s3, s3, DIN, DIN);
}

// Round 19
// 1686.820 us; speedup vs baseline: 1.2219x; 1.1669x over previous
//
#include <hip/hip_runtime.h>
#include <hip/hip_bf16.h>
#include <stdint.h>

typedef __bf16 bf16;
typedef __bf16 bf16x8 __attribute__((ext_vector_type(8)));
typedef float f32x4 __attribute__((ext_vector_type(4)));

typedef uint32_t __attribute__((address_space(1))) * gptr_as1;
typedef uint32_t __attribute__((address_space(3))) * lptr_as3;

__device__ __forceinline__ void async16(const void* g, void* l) {
    __builtin_amdgcn_global_load_lds((gptr_as1)(uintptr_t)g,
                                     (lptr_as3)(uintptr_t)l,
                                     16, 0, 0);
}

__device__ __forceinline__ void bar() {
    asm volatile("" ::: "memory");
    __builtin_amdgcn_s_barrier();
    asm volatile("" ::: "memory");
}

// ---------------------------------------------------------------- cvt f32->bf16
__global__ void cvt_f32_bf16_kernel(const float* __restrict__ src,
                                    bf16* __restrict__ dst, int n8) {
    int i = blockIdx.x * blockDim.x + threadIdx.x;
    if (i >= n8) return;
    const float4* s = reinterpret_cast<const float4*>(src);
    float4 a = s[2 * (size_t)i], b = s[2 * (size_t)i + 1];
    bf16x8 v;
    v[0] = (bf16)a.x; v[1] = (bf16)a.y; v[2] = (bf16)a.z; v[3] = (bf16)a.w;
    v[4] = (bf16)b.x; v[5] = (bf16)b.y; v[6] = (bf16)b.z; v[7] = (bf16)b.w;
    *reinterpret_cast<bf16x8*>(dst + (size_t)i * 8) = v;
}

// cvt + 16-row interleave: src row r (of DHID) -> dst row (r/16)*32 + sel*16 + r%16.
__global__ void cvt_ilv_kernel(const float* __restrict__ src,
                               bf16* __restrict__ dst, int n8, int sel) {
    int i = blockIdx.x * blockDim.x + threadIdx.x;
    if (i >= n8) return;
    const int row = i >> 8;          // / 256  (DIN=2048 -> 256 chunks/row)
    const int c = i & 255;
    const int drow = ((row >> 4) << 5) + (sel << 4) + (row & 15);
    const float4* s = reinterpret_cast<const float4*>(src);
    float4 a = s[2 * (size_t)i], b = s[2 * (size_t)i + 1];
    bf16x8 v;
    v[0] = (bf16)a.x; v[1] = (bf16)a.y; v[2] = (bf16)a.z; v[3] = (bf16)a.w;
    v[4] = (bf16)b.x; v[5] = (bf16)b.y; v[6] = (bf16)b.z; v[7] = (bf16)b.w;
    *reinterpret_cast<bf16x8*>(dst + ((size_t)drow * 256 + c) * 8) = v;
}

// ---------------------------------------------------------------- 256^2 GEMM: wave-slip phases (R15, session best)
// C = A[M,K] * B[N,K]^T. 512 thr / 8 waves (2Mx4N), wave tile 128x64, BK=64.
// LDS 2dbuf x 64KB; zero-VALU base+literal ds_reads (R13); conflicts = 0.
// PHASE = [stage; reads; MFMA; (vmcnt); BARRIER] — reads first in program
// order, NO mid-phase barrier: each wave's MFMA waits only on its OWN reads
// (compiler-counted lgkmcnt) -> waves slip; early-served waves' MFMA overlaps
// later waves' LDS drain.
// Stage safety: stage into region R is safe iff R's last reads were SERVICED
// before the previous barrier — true because the reads' consuming MFMA
// (lgkm-gated) precedes that barrier in the reader's program order.
//   P1 stages A-odd(kt+1)->nA   [last read P4(kt-1)];
//   P4 stages B-h0,h1(kt+2)->cB [last read P3(kt)]
//           + A-even(kt+2)->cA  [last read P3(kt); P4 reads A-odd — disjoint].
// FIFO: end-P4 outstanding = 6(kt+1) + 2(A-odd kt+1 @P1) + 6(kt+2 @P4) = 14
// -> vmcnt(6) lands ALL of kt+1, leaves kt+2's 6. Tail vmcnt(0) @NT-2.
// Measured (R15): GEMM-h 956 us, MfmaUtil 51.4%, SQ_LDS_BANK_CONFLICT 0.
// EPI=0: bf16(gelu(acc*s1)) | EPI=1: f32(acc*s1) | EPI=2: swiglu, 16-col interleave.
template <int EPI, int K>
__global__ __launch_bounds__(512, 1)
void gemm8p(const bf16* __restrict__ A, const bf16* __restrict__ B,
            void* __restrict__ Cout, const float* __restrict__ s1p,
            const float* __restrict__ s2p, int N, int ldh) {
    __shared__ __align__(16) char sm[131072];

    const int tid = threadIdx.x;
    const int w = tid >> 6, l = tid & 63;
    const int wr = w >> 2, wc = w & 3;

    const int gx = gridDim.x;
    const int nwg = gx * (int)gridDim.y;
    const int orig = blockIdx.y * gx + blockIdx.x;
    const int wg = (orig & 7) * (nwg >> 3) + (orig >> 3);
    const int bm = wg / gx, bn = wg % gx;

    constexpr int NT = K / 64;

    f32x4 acc[8][4] = {};

    char* const bufA0 = sm;
    char* const bufB0 = sm + 32768;
    char* const bufA1 = sm + 65536;
    char* const bufB1 = sm + 98304;
    const int arow = bm * 256, brow = bn * 256;

    const int srow_in = l >> 3;
    const int scolb = ((l & 7) ^ srow_in) << 4;
    auto STAGE = [&](char* ldsT, const bf16* g, int grow0, int kt, int r0) {
        const int rr = r0 + w * 8 + srow_in;
        const char* gp = (const char*)(g + (size_t)(grow0 + rr) * K + kt * 64) + scolb;
        async16(gp, ldsT + r0 * 128 + w * 1024);
    };

    const int rlane = l & 15;
    const int chi = (l >> 4) << 4;
    const int sw = (rlane & 7) << 4;
    const int ksd = (rlane & 4) ? -64 : 64;          // (ks=1 col) - (ks=0 col)
    const int offA = (wr * 128 + rlane) * 128 + (chi ^ sw);
    const int offB = (wc * 64 + rlane) * 128 + (chi ^ sw);
    const char* const pA0  = bufA0 + offA;  const char* const pA0k = pA0 + ksd;
    const char* const pB0  = bufB0 + offB;  const char* const pB0k = pB0 + ksd;
    const char* const pA1  = bufA1 + offA;  const char* const pA1k = pA1 + ksd;
    const char* const pB1  = bufB1 + offB;  const char* const pB1k = pB1 + ksd;

    // ---- prologue: tile0 {A-even, B-h0, B-h1, A-odd}; tile1 {A-even, B-h0, B-h1}
    STAGE(bufA0, A, arow, 0, 0);   STAGE(bufA0, A, arow, 0, 128);
    STAGE(bufB0, B, brow, 0, 0);   STAGE(bufB0, B, brow, 0, 64);
    STAGE(bufB0, B, brow, 0, 128); STAGE(bufB0, B, brow, 0, 192);
    STAGE(bufA0, A, arow, 0, 64);  STAGE(bufA0, A, arow, 0, 192);
    STAGE(bufA1, A, arow, 1, 0);   STAGE(bufA1, A, arow, 1, 128);
    STAGE(bufB1, B, brow, 1, 0);   STAGE(bufB1, B, brow, 1, 64);
    STAGE(bufB1, B, brow, 1, 128); STAGE(bufB1, B, brow, 1, 192);
    asm volatile("s_waitcnt vmcnt(6)" ::: "memory");
    bar();

    auto body = [&](int kt, char* cA, char* cB, char* nA,
                    const char* pa, const char* pak,
                    const char* pb, const char* pbk) {
        bf16x8 ae[4], ao[4], bv[4];
        // ---- P1: stage A-odd(kt+1)->nA; reads avE-ks0 + bv-ks0; MFMA; bar
        if (kt + 1 < NT) { STAGE(nA, A, arow, kt + 1, 64); STAGE(nA, A, arow, kt + 1, 192); }
#pragma unroll
        for (int i = 0; i < 4; ++i)
            ae[i] = *reinterpret_cast<const bf16x8*>(pa + i * 2048);
#pragma unroll
        for (int j = 0; j < 4; ++j)
            bv[j] = *reinterpret_cast<const bf16x8*>(pb + j * 2048);
        __builtin_amdgcn_s_setprio(1);
#pragma unroll
        for (int i = 0; i < 4; ++i)
#pragma unroll
            for (int j = 0; j < 4; ++j)
                acc[i][j] = __builtin_amdgcn_mfma_f32_16x16x32_bf16(ae[i], bv[j], acc[i][j], 0, 0, 0);
        __builtin_amdgcn_s_setprio(0);
        bar();
        // ---- P2: reads avO-ks0; MFMA; bar
#pragma unroll
        for (int i = 0; i < 4; ++i)
            ao[i] = *reinterpret_cast<const bf16x8*>(pa + 8192 + i * 2048);
        __builtin_amdgcn_s_setprio(1);
#pragma unroll
        for (int i = 0; i < 4; ++i)
#pragma unroll
            for (int j = 0; j < 4; ++j)
                acc[4 + i][j] = __builtin_amdgcn_mfma_f32_16x16x32_bf16(ao[i], bv[j], acc[4 + i][j], 0, 0, 0);
        __builtin_amdgcn_s_setprio(0);
        bar();
        // ---- P3: reads avE-ks1 + bv-ks1; MFMA; bar
#pragma unroll
        for (int i = 0; i < 4; ++i)
            ae[i] = *reinterpret_cast<const bf16x8*>(pak + i * 2048);
#pragma unroll
        for (int j = 0; j < 4; ++j)
            bv[j] = *reinterpret_cast<const bf16x8*>(pbk + j * 2048);
        __builtin_amdgcn_s_setprio(1);
#pragma unroll
        for (int i = 0; i < 4; ++i)
#pragma unroll
            for (int j = 0; j < 4; ++j)
                acc[i][j] = __builtin_amdgcn_mfma_f32_16x16x32_bf16(ae[i], bv[j], acc[i][j], 0, 0, 0);
        __builtin_amdgcn_s_setprio(0);
        bar();
        // ---- P4: stage B-h0,h1(kt+2)->cB + A-even(kt+2)->cA; reads avO-ks1; MFMA; vmcnt; bar
        if (kt + 2 < NT) {
            STAGE(cB, B, brow, kt + 2, 0);   STAGE(cB, B, brow, kt + 2, 64);
            STAGE(cB, B, brow, kt + 2, 128); STAGE(cB, B, brow, kt + 2, 192);
            STAGE(cA, A, arow, kt + 2, 0);   STAGE(cA, A, arow, kt + 2, 128);
        }
#pragma unroll
        for (int i = 0; i < 4; ++i)
            ao[i] = *reinterpret_cast<const bf16x8*>(pak + 8192 + i * 2048);
        __builtin_amdgcn_s_setprio(1);
#pragma unroll
        for (int i = 0; i < 4; ++i)
#pragma unroll
            for (int j = 0; j < 4; ++j)
                acc[4 + i][j] = __builtin_amdgcn_mfma_f32_16x16x32_bf16(ao[i], bv[j], acc[4 + i][j], 0, 0, 0);
        __builtin_amdgcn_s_setprio(0);
        if (kt == NT - 2) { asm volatile("s_waitcnt vmcnt(0)" ::: "memory"); }
        else              { asm volatile("s_waitcnt vmcnt(6)" ::: "memory"); }
        bar();
    };

#pragma unroll 1
    for (int kt = 0; kt < NT; kt += 2) {
        body(kt,     bufA0, bufB0, bufA1, pA0, pA0k, pB0, pB0k);
        body(kt + 1, bufA1, bufB1, bufA0, pA1, pA1k, pB1, pB1k);
    }

    const float s1 = s1p[0];
    const int r0 = bm * 256 + wr * 128 + ((l >> 4) << 2);
    if constexpr (EPI == 2) {
        const float s2 = s2p[0];
        const int hcb = (bn * 8 + wc * 2) * 16 + rlane;
#pragma unroll
        for (int i = 0; i < 8; ++i)
#pragma unroll
            for (int jp = 0; jp < 2; ++jp)
#pragma unroll
                for (int q = 0; q < 4; ++q) {
                    float g = acc[i][2 * jp][q] * s1;
                    float v = acc[i][2 * jp + 1][q] * s2;
                    float sig = 1.0f / (1.0f + __expf(-g));
                    ((bf16*)Cout)[(size_t)(r0 + i * 16 + q) * ldh + hcb + jp * 16] =
                        (bf16)(g * sig * v);
                }
    } else {
        const int c0 = bn * 256 + wc * 64 + rlane;
#pragma unroll
        for (int i = 0; i < 8; ++i)
#pragma unroll
            for (int j = 0; j < 4; ++j)
#pragma unroll
                for (int q = 0; q < 4; ++q) {
                    float v = acc[i][j][q] * s1;
                    size_t idx = (size_t)(r0 + i * 16 + q) * N + (c0 + j * 16);
                    if constexpr (EPI == 0) {
                        float g = 0.5f * v * (1.0f + erff(v * 0.70710678118654752f));
                        ((bf16*)Cout)[idx] = (bf16)g;
                    } else {
                        ((float*)Cout)[idx] = v;
                    }
                }
    }
}

// ---------------------------------------------------------------- launch
extern "C" void kernel_launch(void* const* d_in, const int* in_sizes, int n_in,
                              void* d_out, int out_size, void* d_ws, size_t ws_size,
                              hipStream_t stream) {
    constexpr int NTOK = 8192, DIN = 2048, DHID = 8192;

    const float* x  = (const float*)d_in[0];
    const float* W1 = (const float*)d_in[1];
    const float* W2 = (const float*)d_in[2];
    const float* Wh = (const float*)d_in[3];
    const float* W3 = (const float*)d_in[4];
    const float* s1 = (const float*)d_in[5];
    const float* s2 = (const float*)d_in[6];
    const float* sh = (const float*)d_in[7];
    const float* s3 = (const float*)d_in[8];
    float* out = (float*)d_out;

    char* ws = (char*)d_ws;
    size_t off = 0;
    bf16* xb   = (bf16*)(ws + off); off += (size_t)NTOK * DIN * 2;
    bf16* w12b = (bf16*)(ws + off); off += (size_t)2 * DHID * DIN * 2;
    bf16* w3b  = (bf16*)(ws + off); off += (size_t)DIN * DHID * 2;
    bf16* whb  = (bf16*)(ws + off); off += (size_t)DHID * DHID * 2;
    bf16* h1   = (bf16*)(ws + off); off += (size_t)NTOK * DHID * 2;
    bf16* h2   = (bf16*)(ws + off); off += (size_t)NTOK * DHID * 2;
    if (ws_size < off) return;

    auto cvt = [&](const float* s, bf16* d, size_t n) {
        int n8 = (int)(n / 8);
        cvt_f32_bf16_kernel<<<(n8 + 255) / 256, 256, 0, stream>>>(s, d, n8);
    };
    cvt(x,  xb,  (size_t)NTOK * DIN);
    cvt(Wh, whb, (size_t)DHID * DHID);
    cvt(W3, w3b, (size_t)DIN * DHID);
    {
        int n8 = (int)((size_t)DHID * DIN / 8);
        cvt_ilv_kernel<<<(n8 + 255) / 256, 256, 0, stream>>>(W1, w12b, n8, 0);
        cvt_ilv_kernel<<<(n8 + 255) / 256, 256, 0, stream>>>(W2, w12b, n8, 1);
    }

    // GEMM1+2 fused: C[8192, 16384] over interleaved W12, SwiGLU epilogue -> h1
    gemm8p<2, DIN><<<dim3(2 * DHID / 256, NTOK / 256), 512, 0, stream>>>(
        xb, w12b, h1, s1, s2, 2 * DHID, DHID);
    // hidden GEMM + gelu -> h2
    gemm8p<0, DHID><<<dim3(DHID / 256, NTOK / 256), 512, 0, stream>>>(
        h1, whb, h2, sh, sh, DHID, DHID);
    // output GEMM -> out (f32)
    gemm8p<1, DHID><<<dim3(DIN / 256, NTOK / 256), 512, 0, stream>>>(
        h2, w3b, out, s3, s3, DIN, DIN);
}